// Round 12
// baseline (114.509 us; speedup 1.0000x reference)
//
#include <hip/hip_runtime.h>
#include <math.h>

#define PI_F 3.14159265358979323846f

typedef _Float16 h16x8 __attribute__((ext_vector_type(8)));
typedef float f32x4 __attribute__((ext_vector_type(4)));
typedef unsigned int u32x4 __attribute__((ext_vector_type(4)));

// Single-dispatch fused kernel (r7 geometry: 64 rows/block, 256 blocks).
// Blocks 0..31 produce U (8 cols each, 1 col/wave) -> flag; all blocks build
// psi, spin on flag (device-scope acquire), then complex GEMM + Walsh epilogue.
// No grid.sync (r5: coop launch costs ~55us). No deadlock: 256 blocks co-resident.
#define APAGE 4112
#define P2STR 146

__device__ __forceinline__ void gpair(float2& a, const float2 p, const int mb,
                                      const float g0x, const float g0y,
                                      const float g1x, const float g1y) {
    const float e0y = mb ? -g0y : g0y;
    const float f1x = mb ? -g1x : g1x;
    const float nx = g0x * a.x - e0y * a.y + f1x * p.x - g1y * p.y;
    const float ny = g0x * a.y + e0y * a.x + f1x * p.y + g1y * p.x;
    a.x = nx; a.y = ny;
}

__device__ __forceinline__ void apply_g(float2 a[4], const int b, const int lane,
                                        const float g0x, const float g0y,
                                        const float g1x, const float g1y) {
    if (b >= 2) {
        const int lb = b - 2;
        const int mb = (lane >> lb) & 1;
#pragma unroll
        for (int j = 0; j < 4; ++j) {
            float2 p;
            p.x = __shfl_xor(a[j].x, 1 << lb, 64);
            p.y = __shfl_xor(a[j].y, 1 << lb, 64);
            gpair(a[j], p, mb, g0x, g0y, g1x, g1y);
        }
    } else if (b == 1) {
        float2 o0 = a[0], o1 = a[1], o2 = a[2], o3 = a[3];
        gpair(a[0], o2, 0, g0x, g0y, g1x, g1y);
        gpair(a[2], o0, 1, g0x, g0y, g1x, g1y);
        gpair(a[1], o3, 0, g0x, g0y, g1x, g1y);
        gpair(a[3], o1, 1, g0x, g0y, g1x, g1y);
    } else {
        float2 o0 = a[0], o1 = a[1], o2 = a[2], o3 = a[3];
        gpair(a[0], o1, 0, g0x, g0y, g1x, g1y);
        gpair(a[1], o0, 1, g0x, g0y, g1x, g1y);
        gpair(a[2], o3, 0, g0x, g0y, g1x, g1y);
        gpair(a[3], o2, 1, g0x, g0y, g1x, g1y);
    }
}

__device__ __forceinline__ void apply_cnot_g(float2 a[4], const int cw, const int lane) {
    if (cw <= 4) {
        const int lt = (6 - cw) - 2;
        const int lc = lt + 1;
        const bool ctrl = ((lane >> lc) & 1) != 0;
#pragma unroll
        for (int j = 0; j < 4; ++j) {
            float px = __shfl_xor(a[j].x, 1 << lt, 64);
            float py = __shfl_xor(a[j].y, 1 << lt, 64);
            a[j].x = ctrl ? px : a[j].x;
            a[j].y = ctrl ? py : a[j].y;
        }
    } else if (cw == 5) {
        const bool ctrl = (lane & 1) != 0;
        float2 t;
        t = a[0]; a[0].x = ctrl ? a[2].x : a[0].x; a[0].y = ctrl ? a[2].y : a[0].y;
        a[2].x = ctrl ? t.x : a[2].x; a[2].y = ctrl ? t.y : a[2].y;
        t = a[1]; a[1].x = ctrl ? a[3].x : a[1].x; a[1].y = ctrl ? a[3].y : a[1].y;
        a[3].x = ctrl ? t.x : a[3].x; a[3].y = ctrl ? t.y : a[3].y;
    } else {
        float2 t = a[2]; a[2] = a[3]; a[3] = t;
    }
}

__device__ __forceinline__ unsigned int packh2(float lo, float hi) {
    unsigned short l = __builtin_bit_cast(unsigned short, (_Float16)lo);
    unsigned short h = __builtin_bit_cast(unsigned short, (_Float16)hi);
    return ((unsigned int)h << 16) | (unsigned int)l;
}

__device__ __forceinline__ float2 cmulf(float2 a, float2 b) {
    return make_float2(a.x * b.x - a.y * b.y, a.x * b.y + a.y * b.x);
}

__device__ __forceinline__ h16x8 negh8(h16x8 v) {
    u32x4 u = __builtin_bit_cast(u32x4, v);
    u ^= (u32x4){0x80008000u, 0x80008000u, 0x80008000u, 0x80008000u};
    return __builtin_bit_cast(h16x8, u);
}

__device__ __forceinline__ void loadB4(h16x8 bf[4], const char* ub, const size_t boff[4],
                                       const int kk) {
#pragma unroll
    for (int f = 0; f < 4; ++f)
        bf[f] = *(const h16x8*)(ub + (size_t)kk * 16384 + boff[f]);
}

__device__ __forceinline__ void loadA8(h16x8 ar[4], h16x8 ai[4], const char* apc,
                                       const unsigned int aoff, const int kk) {
#pragma unroll
    for (int rt = 0; rt < 4; ++rt)
        ar[rt] = *(const h16x8*)(apc + kk * APAGE + rt * 1024 + aoff);
#pragma unroll
    for (int rt = 0; rt < 4; ++rt)
        ai[rt] = *(const h16x8*)(apc + 8 * APAGE + kk * APAGE + rt * 1024 + aoff);
}

__device__ __forceinline__ void mfma32(f32x4 aR[4][2], f32x4 aI[4][2],
                                       const h16x8 ar[4], const h16x8 ai[4],
                                       const h16x8 bf[4]) {
#pragma unroll
    for (int rt = 0; rt < 4; ++rt) {
        const h16x8 nai = negh8(ai[rt]);
#pragma unroll
        for (int cf = 0; cf < 2; ++cf) {
            aR[rt][cf] = __builtin_amdgcn_mfma_f32_16x16x32_f16(ar[rt], bf[cf],
                                                                aR[rt][cf], 0, 0, 0);
            aR[rt][cf] = __builtin_amdgcn_mfma_f32_16x16x32_f16(nai, bf[2 + cf],
                                                                aR[rt][cf], 0, 0, 0);
            aI[rt][cf] = __builtin_amdgcn_mfma_f32_16x16x32_f16(ai[rt], bf[cf],
                                                                aI[rt][cf], 0, 0, 0);
            aI[rt][cf] = __builtin_amdgcn_mfma_f32_16x16x32_f16(ar[rt], bf[2 + cf],
                                                                aI[rt][cf], 0, 0, 0);
        }
    }
}

// ---------------------------------------------------------------------------
// Fused kernel: 64 samples/block, 256 blocks, 512 threads.
// ---------------------------------------------------------------------------
__global__ __launch_bounds__(512, 2) void fused_kernel(const float* __restrict__ x,
                                                       const float* __restrict__ w,
                                                       unsigned short* __restrict__ ub16,
                                                       unsigned int* __restrict__ flag,
                                                       float* __restrict__ out) {
    // union: A-tile (65792 B) during GEMM, P2 matrix (74752 B) in epilogue
    __shared__ __align__(16) char smem[64 * P2STR * 8];
    __shared__ float wc[48];
    __shared__ float wsn[48];

    const int tid = threadIdx.x;
    const int bid = blockIdx.x;
    const int lane = tid & 63;
    const int wv = tid >> 6;        // 0..7
    const int c15 = lane & 15;
    const int g = lane >> 4;

    // ---------------- producer: blocks 0..31 build U (1 col/wave) ----------------
    if (bid < 32) {
        if (tid < 48) {
            float s, c;
            __sincosf(w[tid] * 0.5f, &s, &c);
            wc[tid] = c; wsn[tid] = s;
        }
        __syncthreads();

        const int n = bid * 8 + wv;   // column 0..255

        // layer 0 closed form: amp[m] = prod_q G_q[v_q][n_q], v = m ^ (m>>1)
        float2 e0q[8], e1q[8];
#pragma unroll
        for (int q = 0; q < 8; ++q) {
            const int k = 2 * q;
            const float c0 = wc[k], s0 = wsn[k];
            const float c1 = wc[k + 1], s1 = wsn[k + 1];
            const float2 g0 = make_float2(c1 * c0, s1 * s0);
            const float2 g1 = make_float2(-s1 * c0, -c1 * s0);
            const int nq = (n >> (7 - q)) & 1;
            e0q[q] = nq ? g1 : g0;
            e1q[q] = nq ? make_float2(g0.x, -g0.y)
                        : make_float2(-g1.x, g1.y);
        }

        float2 a[4];
#pragma unroll
        for (int j = 0; j < 4; ++j) {
            const int m = lane * 4 + j;
            const int v = m ^ (m >> 1);
            float2 acc = ((v >> 7) & 1) ? e1q[0] : e0q[0];
#pragma unroll
            for (int q = 1; q < 8; ++q)
                acc = cmulf(acc, ((v >> (7 - q)) & 1) ? e1q[q] : e0q[q]);
            a[j] = acc;
        }

#pragma unroll
        for (int L = 1; L < 3; ++L) {
#pragma unroll
            for (int q = 0; q < 8; ++q) {
                const int k = 2 * (L * 8 + q);
                const float c0 = wc[k], s0 = wsn[k];
                const float c1 = wc[k + 1], s1 = wsn[k + 1];
                const float g0x = c1 * c0, g0y = s1 * s0;
                const float g1x = -s1 * c0, g1y = -c1 * s0;
                apply_g(a, 7 - q, lane, g0x, g0y, g1x, g1y);
            }
#pragma unroll
            for (int cwire = 0; cwire < 7; ++cwire) apply_cnot_g(a, cwire, lane);
        }

        const int base = (n >> 5) * 8192 + (n & 31);
#pragma unroll
        for (int j = 0; j < 4; ++j) {
            const int m = lane * 4 + j;
            ub16[base + m * 32] =
                __builtin_bit_cast(unsigned short, (_Float16)a[j].x);      // Re U[m][n]
            ub16[65536 + base + m * 32] =
                __builtin_bit_cast(unsigned short, (_Float16)a[j].y);      // Im U[m][n]
        }
        __threadfence();              // release: publish U device-wide
        __syncthreads();              // all 8 waves done
        if (tid == 0)
            __hip_atomic_fetch_add(flag, 1u, __ATOMIC_RELEASE, __HIP_MEMORY_SCOPE_AGENT);
    }

    // ---------------- phase 1: psi tile build (all blocks) ----------------
    {
        const int row = tid >> 3;          // 0..63 (sample row)
        const int t8 = tid & 7;            // n bits 7..5 -> page index
        const int grow = bid * 64 + row;

        const float4* xp = (const float4*)(x + grow * 8);
        float4 xa = xp[0], xb = xp[1];
        float ang[8] = {xa.x, xa.y, xa.z, xa.w, xb.x, xb.y, xb.z, xb.w};

        float2 v0[8], v1[8];
#pragma unroll
        for (int i = 0; i < 8; ++i) {
            float s, c;
            __sincosf(ang[i] * (PI_F * 0.5f), &s, &c);
            v0[i] = make_float2(c * c, -c * s);
            v1[i] = make_float2(s * c, s * s);
        }

        float2 pre = (t8 & 4) ? v1[0] : v0[0];
        pre = cmulf(pre, (t8 & 2) ? v1[1] : v0[1]);
        pre = cmulf(pre, (t8 & 1) ? v1[2] : v0[2]);

        const int swz = (row >> 1) & 3;
        char* reb = smem + t8 * APAGE + row * 64;
        char* imb = smem + (8 + t8) * APAGE + row * 64;

#pragma unroll
        for (int b4 = 0; b4 < 2; ++b4) {
            float2 p3 = cmulf(pre, b4 ? v1[3] : v0[3]);
#pragma unroll
            for (int b3 = 0; b3 < 2; ++b3) {
                float2 p4 = cmulf(p3, b3 ? v1[4] : v0[4]);
                u32x4 qre, qim;
#pragma unroll
                for (int b2 = 0; b2 < 2; ++b2) {
                    float2 p5 = cmulf(p4, b2 ? v1[5] : v0[5]);
#pragma unroll
                    for (int b1 = 0; b1 < 2; ++b1) {
                        float2 p6 = cmulf(p5, b1 ? v1[6] : v0[6]);
                        const float2 amp0 = cmulf(p6, v0[7]);
                        const float2 amp1 = cmulf(p6, v1[7]);
                        const int pos = (b2 << 1) | b1;
                        qre[pos] = packh2(amp0.x, amp1.x);
                        qim[pos] = packh2(amp0.y, amp1.y);
                    }
                }
                const int c = (b4 << 1) | b3;
                *(u32x4*)(reb + ((c ^ swz) * 16)) = qre;
                *(u32x4*)(imb + ((c ^ swz) * 16)) = qim;
            }
        }
    }
    __syncthreads();

    // ---------------- spin: wait for all 32 producer blocks ----------------
    if (tid == 0) {
        while (__hip_atomic_load(flag, __ATOMIC_ACQUIRE, __HIP_MEMORY_SCOPE_AGENT) < 32u) {
            __builtin_amdgcn_s_sleep(2);
        }
    }
    __syncthreads();
    __threadfence();   // discard stale cached U lines before B loads

    // ---------------- phase 2: complex GEMM (depth-4 B ring) ----------------
    const char* ub = (const char*)ub16;
    size_t boff[4];
    {
        const int cb0 = wv * 32;
        boff[0] = (size_t)(cb0 + c15) * 64 + g * 16;              // Br cf0
        boff[1] = (size_t)(cb0 + 16 + c15) * 64 + g * 16;         // Br cf1
        boff[2] = 131072 + boff[0];                               // Bi cf0
        boff[3] = 131072 + boff[1];                               // Bi cf1
    }
    const unsigned int aoff = c15 * 64 + ((g ^ ((c15 >> 1) & 3)) * 16);
    const char* apc = (const char*)smem;

    h16x8 b0[4], b1[4], b2[4], b3[4];
    loadB4(b0, ub, boff, 0);
    loadB4(b1, ub, boff, 1);
    loadB4(b2, ub, boff, 2);
    loadB4(b3, ub, boff, 3);

    f32x4 aR[4][2], aI[4][2];
#pragma unroll
    for (int rt = 0; rt < 4; ++rt)
#pragma unroll
        for (int cf = 0; cf < 2; ++cf) {
            f32x4 z = {0.f, 0.f, 0.f, 0.f};
            aR[rt][cf] = z; aI[rt][cf] = z;
        }

    h16x8 ar0[4], ai0[4], ar1[4], ai1[4];
    loadA8(ar0, ai0, apc, aoff, 0);

    loadA8(ar1, ai1, apc, aoff, 1);  mfma32(aR, aI, ar0, ai0, b0);  loadB4(b0, ub, boff, 4);
    loadA8(ar0, ai0, apc, aoff, 2);  mfma32(aR, aI, ar1, ai1, b1);  loadB4(b1, ub, boff, 5);
    loadA8(ar1, ai1, apc, aoff, 3);  mfma32(aR, aI, ar0, ai0, b2);  loadB4(b2, ub, boff, 6);
    loadA8(ar0, ai0, apc, aoff, 4);  mfma32(aR, aI, ar1, ai1, b3);  loadB4(b3, ub, boff, 7);
    loadA8(ar1, ai1, apc, aoff, 5);  mfma32(aR, aI, ar0, ai0, b0);
    loadA8(ar0, ai0, apc, aoff, 6);  mfma32(aR, aI, ar1, ai1, b1);
    loadA8(ar1, ai1, apc, aoff, 7);  mfma32(aR, aI, ar0, ai0, b2);
                                     mfma32(aR, aI, ar1, ai1, b3);

    __syncthreads();   // all A-tile LDS reads done before P2 (aliased) writes

    // ---------------- phase 3a: dump p-pairs to P2 ----------------
    // m = wv*32 + cf*16 + c15 ; bit7..5 = wv, bit4 = cf, bits3..0 = c15
    {
        float2* P2 = (float2*)smem;
#pragma unroll
        for (int rt = 0; rt < 4; ++rt) {
#pragma unroll
            for (int r = 0; r < 4; ++r) {
                const float p0 = aR[rt][0][r] * aR[rt][0][r] + aI[rt][0][r] * aI[rt][0][r];
                const float p1 = aR[rt][1][r] * aR[rt][1][r] + aI[rt][1][r] * aI[rt][1][r];
                const int row = rt * 16 + g * 4 + r;
                P2[row * P2STR + wv * 18 + c15] = make_float2(p0, p1);
            }
        }
    }
    __syncthreads();

    // ---------------- phase 3b: in-thread Walsh + wv-shuffle reduce ----------------
    {
        const float2* P2 = (const float2*)smem;
        const int row = tid >> 3;
        const int w2 = tid & 7;

        const float4* base = (const float4*)(P2 + row * P2STR + w2 * 18);
        float S[16], D[16];
#pragma unroll
        for (int k = 0; k < 8; ++k) {
            const float4 q = base[k];
            S[2 * k]     = q.x + q.y;  D[2 * k]     = q.x - q.y;
            S[2 * k + 1] = q.z + q.w;  D[2 * k + 1] = q.z - q.w;
        }
        float s2[8], w1p[8];
#pragma unroll
        for (int k = 0; k < 8; ++k) { s2[k] = S[2*k] + S[2*k+1]; w1p[k] = S[2*k] - S[2*k+1]; }
        float s4[4], w2p[4];
#pragma unroll
        for (int k = 0; k < 4; ++k) { s4[k] = s2[2*k] + s2[2*k+1]; w2p[k] = s2[2*k] - s2[2*k+1]; }
        const float s8a = s4[0] + s4[1], s8b = s4[2] + s4[3];
        const float W0 = s8a + s8b;
        const float W8 = s8a - s8b;
        const float W4 = (s4[0] - s4[1]) + (s4[2] - s4[3]);
        const float W2 = w2p[0] + w2p[1] + w2p[2] + w2p[3];
        float W1 = 0.f, Sd = 0.f;
#pragma unroll
        for (int k = 0; k < 8; ++k) { W1 += w1p[k]; Sd += D[2*k] + D[2*k+1]; }

        float zp[8];
        zp[0] = (w2 & 4) ? -W0 : W0;   // wire 0 <-> bit 7 (wv bit 2)
        zp[1] = (w2 & 2) ? -W0 : W0;   // wire 1
        zp[2] = (w2 & 1) ? -W0 : W0;   // wire 2
        zp[3] = Sd;                    // wire 3 <-> cf
        zp[4] = W8;                    // wire 4 <-> c15 bit 3
        zp[5] = W4;
        zp[6] = W2;
        zp[7] = W1;

#pragma unroll
        for (int i = 0; i < 8; ++i) {
            zp[i] += __shfl_xor(zp[i], 1, 64);
            zp[i] += __shfl_xor(zp[i], 2, 64);
            zp[i] += __shfl_xor(zp[i], 4, 64);
        }

        if (w2 == 0) {
            float* po = out + (size_t)(bid * 64 + row) * 8;
            *(float4*)po       = make_float4(zp[0], zp[1], zp[2], zp[3]);
            *(float4*)(po + 4) = make_float4(zp[4], zp[5], zp[6], zp[7]);
        }
    }
}

extern "C" void kernel_launch(void* const* d_in, const int* in_sizes, int n_in,
                              void* d_out, int out_size, void* d_ws, size_t ws_size,
                              hipStream_t stream) {
    const float* x = (const float*)d_in[0];
    const float* w = (const float*)d_in[1];
    float* out = (float*)d_out;
    const int B = in_sizes[0] / 8;

    unsigned short* ub16 = (unsigned short*)d_ws;               // 256 KB: Upack
    unsigned int* flag = (unsigned int*)((char*)d_ws + 262144); // 4 B: ready-flag

    hipMemsetAsync(flag, 0, 4, stream);                         // reset each call
    fused_kernel<<<B / 64, 512, 0, stream>>>(x, w, ub16, flag, out);
}

// Round 13
// 20.421 us; speedup vs baseline: 5.6073x; 5.6073x over previous
//
#include <hip/hip_runtime.h>
#include <math.h>

#define PI_F 3.14159265358979323846f

typedef _Float16 h16x8 __attribute__((ext_vector_type(8)));
typedef float f32x4 __attribute__((ext_vector_type(4)));
typedef unsigned int u32x4 __attribute__((ext_vector_type(4)));

// FINAL (r7 structure, best measured: 20.49 us).
// Two dispatches: ubuild (U via closed-form layer0 + 2 simulated layers) then
// gemm (complex MFMA GEMM vs L2-resident Upack + in-thread Walsh epilogue).
// Falsified alternatives: coop grid.sync (+55us, r3/r5), spin-wait fusion
// (+95us, r12), M-split 2 blocks/CU (net +1us: L2 B-traffic doubles, r11),
// launch_bounds(512,8) (64-VGPR spill storm, r9), depth-2 B-ring (fail, r10).
#define APAGE 4112
#define P2STR 146

__device__ __forceinline__ void gpair(float2& a, const float2 p, const int mb,
                                      const float g0x, const float g0y,
                                      const float g1x, const float g1y) {
    const float e0y = mb ? -g0y : g0y;
    const float f1x = mb ? -g1x : g1x;
    const float nx = g0x * a.x - e0y * a.y + f1x * p.x - g1y * p.y;
    const float ny = g0x * a.y + e0y * a.x + f1x * p.y + g1y * p.x;
    a.x = nx; a.y = ny;
}

__device__ __forceinline__ void apply_g(float2 a[4], const int b, const int lane,
                                        const float g0x, const float g0y,
                                        const float g1x, const float g1y) {
    if (b >= 2) {
        const int lb = b - 2;
        const int mb = (lane >> lb) & 1;
#pragma unroll
        for (int j = 0; j < 4; ++j) {
            float2 p;
            p.x = __shfl_xor(a[j].x, 1 << lb, 64);
            p.y = __shfl_xor(a[j].y, 1 << lb, 64);
            gpair(a[j], p, mb, g0x, g0y, g1x, g1y);
        }
    } else if (b == 1) {
        float2 o0 = a[0], o1 = a[1], o2 = a[2], o3 = a[3];
        gpair(a[0], o2, 0, g0x, g0y, g1x, g1y);
        gpair(a[2], o0, 1, g0x, g0y, g1x, g1y);
        gpair(a[1], o3, 0, g0x, g0y, g1x, g1y);
        gpair(a[3], o1, 1, g0x, g0y, g1x, g1y);
    } else {
        float2 o0 = a[0], o1 = a[1], o2 = a[2], o3 = a[3];
        gpair(a[0], o1, 0, g0x, g0y, g1x, g1y);
        gpair(a[1], o0, 1, g0x, g0y, g1x, g1y);
        gpair(a[2], o3, 0, g0x, g0y, g1x, g1y);
        gpair(a[3], o2, 1, g0x, g0y, g1x, g1y);
    }
}

__device__ __forceinline__ void apply_cnot_g(float2 a[4], const int cw, const int lane) {
    if (cw <= 4) {
        const int lt = (6 - cw) - 2;
        const int lc = lt + 1;
        const bool ctrl = ((lane >> lc) & 1) != 0;
#pragma unroll
        for (int j = 0; j < 4; ++j) {
            float px = __shfl_xor(a[j].x, 1 << lt, 64);
            float py = __shfl_xor(a[j].y, 1 << lt, 64);
            a[j].x = ctrl ? px : a[j].x;
            a[j].y = ctrl ? py : a[j].y;
        }
    } else if (cw == 5) {
        const bool ctrl = (lane & 1) != 0;
        float2 t;
        t = a[0]; a[0].x = ctrl ? a[2].x : a[0].x; a[0].y = ctrl ? a[2].y : a[0].y;
        a[2].x = ctrl ? t.x : a[2].x; a[2].y = ctrl ? t.y : a[2].y;
        t = a[1]; a[1].x = ctrl ? a[3].x : a[1].x; a[1].y = ctrl ? a[3].y : a[1].y;
        a[3].x = ctrl ? t.x : a[3].x; a[3].y = ctrl ? t.y : a[3].y;
    } else {
        float2 t = a[2]; a[2] = a[3]; a[3] = t;
    }
}

__device__ __forceinline__ unsigned int packh2(float lo, float hi) {
    unsigned short l = __builtin_bit_cast(unsigned short, (_Float16)lo);
    unsigned short h = __builtin_bit_cast(unsigned short, (_Float16)hi);
    return ((unsigned int)h << 16) | (unsigned int)l;
}

__device__ __forceinline__ float2 cmulf(float2 a, float2 b) {
    return make_float2(a.x * b.x - a.y * b.y, a.x * b.y + a.y * b.x);
}

__device__ __forceinline__ h16x8 negh8(h16x8 v) {
    u32x4 u = __builtin_bit_cast(u32x4, v);
    u ^= (u32x4){0x80008000u, 0x80008000u, 0x80008000u, 0x80008000u};
    return __builtin_bit_cast(h16x8, u);
}

// ---------------------------------------------------------------------------
// Kernel 1: build complex-packed U (256 KB in d_ws). One block = one wave =
// one column n. Layer 0 closed form: amp[m] = prod_q G_q[v_q][n_q],
// v = m ^ (m>>1) (CNOT ladder = prefix-XOR = Gray map). Layers 1,2 simulated.
// ---------------------------------------------------------------------------
__global__ __launch_bounds__(64) void ubuild_kernel(const float* __restrict__ w,
                                                    unsigned short* __restrict__ ub16) {
    __shared__ float wc[48];
    __shared__ float wsn[48];
    const int tid = threadIdx.x;
    if (tid < 48) {
        float s, c;
        __sincosf(w[tid] * 0.5f, &s, &c);
        wc[tid] = c; wsn[tid] = s;
    }
    __syncthreads();

    const int lane = tid;
    const int n = blockIdx.x;

    float2 e0q[8], e1q[8];
#pragma unroll
    for (int q = 0; q < 8; ++q) {
        const int k = 2 * q;
        const float c0 = wc[k], s0 = wsn[k];
        const float c1 = wc[k + 1], s1 = wsn[k + 1];
        const float2 g0 = make_float2(c1 * c0, s1 * s0);
        const float2 g1 = make_float2(-s1 * c0, -c1 * s0);
        const int nq = (n >> (7 - q)) & 1;
        e0q[q] = nq ? g1 : g0;
        e1q[q] = nq ? make_float2(g0.x, -g0.y)
                    : make_float2(-g1.x, g1.y);
    }

    float2 a[4];
#pragma unroll
    for (int j = 0; j < 4; ++j) {
        const int m = lane * 4 + j;
        const int v = m ^ (m >> 1);
        float2 acc = ((v >> 7) & 1) ? e1q[0] : e0q[0];
#pragma unroll
        for (int q = 1; q < 8; ++q)
            acc = cmulf(acc, ((v >> (7 - q)) & 1) ? e1q[q] : e0q[q]);
        a[j] = acc;
    }

#pragma unroll
    for (int L = 1; L < 3; ++L) {
#pragma unroll
        for (int q = 0; q < 8; ++q) {
            const int k = 2 * (L * 8 + q);
            const float c0 = wc[k], s0 = wsn[k];
            const float c1 = wc[k + 1], s1 = wsn[k + 1];
            const float g0x = c1 * c0, g0y = s1 * s0;
            const float g1x = -s1 * c0, g1y = -c1 * s0;
            apply_g(a, 7 - q, lane, g0x, g0y, g1x, g1y);
        }
#pragma unroll
        for (int cwire = 0; cwire < 7; ++cwire) apply_cnot_g(a, cwire, lane);
    }

    const int base = (n >> 5) * 8192 + (n & 31);
#pragma unroll
    for (int j = 0; j < 4; ++j) {
        const int m = lane * 4 + j;
        ub16[base + m * 32] =
            __builtin_bit_cast(unsigned short, (_Float16)a[j].x);          // Re U[m][n]
        ub16[65536 + base + m * 32] =
            __builtin_bit_cast(unsigned short, (_Float16)a[j].y);          // Im U[m][n]
    }
}

__device__ __forceinline__ void loadB4(h16x8 bf[4], const char* ub, const size_t boff[4],
                                       const int kk) {
#pragma unroll
    for (int f = 0; f < 4; ++f)
        bf[f] = *(const h16x8*)(ub + (size_t)kk * 16384 + boff[f]);
}

__device__ __forceinline__ void loadA8(h16x8 ar[4], h16x8 ai[4], const char* apc,
                                       const unsigned int aoff, const int kk) {
#pragma unroll
    for (int rt = 0; rt < 4; ++rt)
        ar[rt] = *(const h16x8*)(apc + kk * APAGE + rt * 1024 + aoff);
#pragma unroll
    for (int rt = 0; rt < 4; ++rt)
        ai[rt] = *(const h16x8*)(apc + 8 * APAGE + kk * APAGE + rt * 1024 + aoff);
}

__device__ __forceinline__ void mfma32(f32x4 aR[4][2], f32x4 aI[4][2],
                                       const h16x8 ar[4], const h16x8 ai[4],
                                       const h16x8 bf[4]) {
#pragma unroll
    for (int rt = 0; rt < 4; ++rt) {
        const h16x8 nai = negh8(ai[rt]);
#pragma unroll
        for (int cf = 0; cf < 2; ++cf) {
            aR[rt][cf] = __builtin_amdgcn_mfma_f32_16x16x32_f16(ar[rt], bf[cf],
                                                                aR[rt][cf], 0, 0, 0);
            aR[rt][cf] = __builtin_amdgcn_mfma_f32_16x16x32_f16(nai, bf[2 + cf],
                                                                aR[rt][cf], 0, 0, 0);
            aI[rt][cf] = __builtin_amdgcn_mfma_f32_16x16x32_f16(ai[rt], bf[cf],
                                                                aI[rt][cf], 0, 0, 0);
            aI[rt][cf] = __builtin_amdgcn_mfma_f32_16x16x32_f16(ar[rt], bf[2 + cf],
                                                                aI[rt][cf], 0, 0, 0);
        }
    }
}

// ---------------------------------------------------------------------------
// Kernel 2: 64 samples/block. B-ring prefetch hoisted above psi (cold-miss
// hides under psi-build). Complex GEMM, LDS-transpose Walsh epilogue.
// ---------------------------------------------------------------------------
__global__ __launch_bounds__(512, 2) void gemm_kernel(const float* __restrict__ x,
                                                      const unsigned short* __restrict__ upack,
                                                      float* __restrict__ out) {
    // union: A-tile (65792 B) during GEMM, P2 matrix (74752 B) in epilogue
    __shared__ __align__(16) char smem[64 * P2STR * 8];

    const int tid = threadIdx.x;
    const int lane = tid & 63;
    const int wv = tid >> 6;        // 0..7 : complex cols [wv*32, wv*32+32)
    const int c15 = lane & 15;
    const int g = lane >> 4;

    // ---------------- phase 0: B-ring prefetch (before psi) ----------------
    const char* ub = (const char*)upack;
    size_t boff[4];
    {
        const int cb0 = wv * 32;
        boff[0] = (size_t)(cb0 + c15) * 64 + g * 16;              // Br cf0
        boff[1] = (size_t)(cb0 + 16 + c15) * 64 + g * 16;         // Br cf1
        boff[2] = 131072 + boff[0];                               // Bi cf0
        boff[3] = 131072 + boff[1];                               // Bi cf1
    }
    h16x8 b0[4], b1[4], b2[4], b3[4];
    loadB4(b0, ub, boff, 0);
    loadB4(b1, ub, boff, 1);
    loadB4(b2, ub, boff, 2);
    loadB4(b3, ub, boff, 3);

    // ---------------- phase 1: psi tile build ----------------
    {
        const int row = tid >> 3;          // 0..63 (sample row)
        const int t8 = tid & 7;            // n bits 7..5 -> page index
        const int grow = blockIdx.x * 64 + row;

        const float4* xp = (const float4*)(x + grow * 8);
        float4 xa = xp[0], xb = xp[1];
        float ang[8] = {xa.x, xa.y, xa.z, xa.w, xb.x, xb.y, xb.z, xb.w};

        float2 v0[8], v1[8];
#pragma unroll
        for (int i = 0; i < 8; ++i) {
            float s, c;
            __sincosf(ang[i] * (PI_F * 0.5f), &s, &c);
            v0[i] = make_float2(c * c, -c * s);
            v1[i] = make_float2(s * c, s * s);
        }

        float2 pre = (t8 & 4) ? v1[0] : v0[0];
        pre = cmulf(pre, (t8 & 2) ? v1[1] : v0[1]);
        pre = cmulf(pre, (t8 & 1) ? v1[2] : v0[2]);

        const int swz = (row >> 1) & 3;
        char* reb = smem + t8 * APAGE + row * 64;
        char* imb = smem + (8 + t8) * APAGE + row * 64;

#pragma unroll
        for (int b4 = 0; b4 < 2; ++b4) {
            float2 p3 = cmulf(pre, b4 ? v1[3] : v0[3]);
#pragma unroll
            for (int b3 = 0; b3 < 2; ++b3) {
                float2 p4 = cmulf(p3, b3 ? v1[4] : v0[4]);
                u32x4 qre, qim;
#pragma unroll
                for (int b2 = 0; b2 < 2; ++b2) {
                    float2 p5 = cmulf(p4, b2 ? v1[5] : v0[5]);
#pragma unroll
                    for (int b1 = 0; b1 < 2; ++b1) {
                        float2 p6 = cmulf(p5, b1 ? v1[6] : v0[6]);
                        const float2 amp0 = cmulf(p6, v0[7]);
                        const float2 amp1 = cmulf(p6, v1[7]);
                        const int pos = (b2 << 1) | b1;
                        qre[pos] = packh2(amp0.x, amp1.x);
                        qim[pos] = packh2(amp0.y, amp1.y);
                    }
                }
                const int c = (b4 << 1) | b3;
                *(u32x4*)(reb + ((c ^ swz) * 16)) = qre;
                *(u32x4*)(imb + ((c ^ swz) * 16)) = qim;
            }
        }
    }
    __syncthreads();

    // ---------------- phase 2: complex GEMM ----------------
    const unsigned int aoff = c15 * 64 + ((g ^ ((c15 >> 1) & 3)) * 16);
    const char* apc = (const char*)smem;

    f32x4 aR[4][2], aI[4][2];
#pragma unroll
    for (int rt = 0; rt < 4; ++rt)
#pragma unroll
        for (int cf = 0; cf < 2; ++cf) {
            f32x4 z = {0.f, 0.f, 0.f, 0.f};
            aR[rt][cf] = z; aI[rt][cf] = z;
        }

    h16x8 ar0[4], ai0[4], ar1[4], ai1[4];
    loadA8(ar0, ai0, apc, aoff, 0);

    loadA8(ar1, ai1, apc, aoff, 1);  mfma32(aR, aI, ar0, ai0, b0);  loadB4(b0, ub, boff, 4);
    loadA8(ar0, ai0, apc, aoff, 2);  mfma32(aR, aI, ar1, ai1, b1);  loadB4(b1, ub, boff, 5);
    loadA8(ar1, ai1, apc, aoff, 3);  mfma32(aR, aI, ar0, ai0, b2);  loadB4(b2, ub, boff, 6);
    loadA8(ar0, ai0, apc, aoff, 4);  mfma32(aR, aI, ar1, ai1, b3);  loadB4(b3, ub, boff, 7);
    loadA8(ar1, ai1, apc, aoff, 5);  mfma32(aR, aI, ar0, ai0, b0);
    loadA8(ar0, ai0, apc, aoff, 6);  mfma32(aR, aI, ar1, ai1, b1);
    loadA8(ar1, ai1, apc, aoff, 7);  mfma32(aR, aI, ar0, ai0, b2);
                                     mfma32(aR, aI, ar1, ai1, b3);

    __syncthreads();   // all A-tile LDS reads done before P2 (aliased) writes

    // ---------------- phase 3a: dump p-pairs to P2 ----------------
    // m = wv*32 + cf*16 + c15 ; bit7..5 = wv, bit4 = cf, bits3..0 = c15
    {
        float2* P2 = (float2*)smem;
#pragma unroll
        for (int rt = 0; rt < 4; ++rt) {
#pragma unroll
            for (int r = 0; r < 4; ++r) {
                const float p0 = aR[rt][0][r] * aR[rt][0][r] + aI[rt][0][r] * aI[rt][0][r];
                const float p1 = aR[rt][1][r] * aR[rt][1][r] + aI[rt][1][r] * aI[rt][1][r];
                const int row = rt * 16 + g * 4 + r;
                P2[row * P2STR + wv * 18 + c15] = make_float2(p0, p1);
            }
        }
    }
    __syncthreads();

    // ---------------- phase 3b: in-thread Walsh + wv-shuffle reduce ----------------
    {
        const float2* P2 = (const float2*)smem;
        const int row = tid >> 3;
        const int w2 = tid & 7;

        const float4* base = (const float4*)(P2 + row * P2STR + w2 * 18);
        float S[16], D[16];
#pragma unroll
        for (int k = 0; k < 8; ++k) {
            const float4 q = base[k];      // {p0_c, p1_c, p0_c+1, p1_c+1}, c = 2k
            S[2 * k]     = q.x + q.y;  D[2 * k]     = q.x - q.y;
            S[2 * k + 1] = q.z + q.w;  D[2 * k + 1] = q.z - q.w;
        }
        float s2[8], w1p[8];
#pragma unroll
        for (int k = 0; k < 8; ++k) { s2[k] = S[2*k] + S[2*k+1]; w1p[k] = S[2*k] - S[2*k+1]; }
        float s4[4], w2p[4];
#pragma unroll
        for (int k = 0; k < 4; ++k) { s4[k] = s2[2*k] + s2[2*k+1]; w2p[k] = s2[2*k] - s2[2*k+1]; }
        const float s8a = s4[0] + s4[1], s8b = s4[2] + s4[3];
        const float W0 = s8a + s8b;
        const float W8 = s8a - s8b;
        const float W4 = (s4[0] - s4[1]) + (s4[2] - s4[3]);
        const float W2 = w2p[0] + w2p[1] + w2p[2] + w2p[3];
        float W1 = 0.f, Sd = 0.f;
#pragma unroll
        for (int k = 0; k < 8; ++k) { W1 += w1p[k]; Sd += D[2*k] + D[2*k+1]; }

        float zp[8];
        zp[0] = (w2 & 4) ? -W0 : W0;   // wire 0 <-> bit 7 (wv bit 2)
        zp[1] = (w2 & 2) ? -W0 : W0;   // wire 1
        zp[2] = (w2 & 1) ? -W0 : W0;   // wire 2
        zp[3] = Sd;                    // wire 3 <-> cf
        zp[4] = W8;                    // wire 4 <-> c15 bit 3
        zp[5] = W4;
        zp[6] = W2;
        zp[7] = W1;

#pragma unroll
        for (int i = 0; i < 8; ++i) {
            zp[i] += __shfl_xor(zp[i], 1, 64);
            zp[i] += __shfl_xor(zp[i], 2, 64);
            zp[i] += __shfl_xor(zp[i], 4, 64);
        }

        if (w2 == 0) {
            float* po = out + (size_t)(blockIdx.x * 64 + row) * 8;
            *(float4*)po       = make_float4(zp[0], zp[1], zp[2], zp[3]);
            *(float4*)(po + 4) = make_float4(zp[4], zp[5], zp[6], zp[7]);
        }
    }
}

extern "C" void kernel_launch(void* const* d_in, const int* in_sizes, int n_in,
                              void* d_out, int out_size, void* d_ws, size_t ws_size,
                              hipStream_t stream) {
    const float* x = (const float*)d_in[0];
    const float* w = (const float*)d_in[1];
    float* out = (float*)d_out;
    const int B = in_sizes[0] / 8;

    unsigned short* ub16 = (unsigned short*)d_ws;       // 256 KB used
    ubuild_kernel<<<256, 64, 0, stream>>>(w, ub16);

    gemm_kernel<<<B / 64, 512, 0, stream>>>(x, (const unsigned short*)d_ws, out);
}